// Round 6
// baseline (95.307 us; speedup 1.0000x reference)
//
#include <hip/hip_runtime.h>

constexpr int Bb = 32;
constexpr int L  = 192;
constexpr int Dk = 1024;
constexpr size_t A1 = (size_t)Bb * L * L;   // elems of one attn matrix
constexpr size_t C1 = (size_t)Bb * L * Dk;  // elems of one attended matrix

typedef short bf16x8 __attribute__((ext_vector_type(8)));
typedef float f32x4  __attribute__((ext_vector_type(4)));
typedef unsigned short ushort_t;

__device__ __forceinline__ unsigned short f2bf(float x){
  unsigned u = __float_as_uint(x);
  u = (u + 0x7FFFu + ((u >> 16) & 1u)) >> 16;
  return (unsigned short)u;
}
__device__ __forceinline__ bf16x8 ldfrag(const unsigned short* p){
  return *reinterpret_cast<const bf16x8*>(p);
}
// pack bf16-truncations of (a,b) into one u32: low16 = hi-bits(a), high16 = hi-bits(b)
__device__ __forceinline__ unsigned pack_hi16(unsigned ua, unsigned ub){
  return __builtin_amdgcn_perm(ua, ub, 0x03020706u);
}

// ---- kernel 1: split-K similarity, reg-prefetch pipeline + XCD swizzle -----
// LDS tiles are [64][64] shorts with a 16B-block XOR swizzle: block index
// (col>>3) is XORed with (row&7) on BOTH the write and read side. Row stride
// 128 B => 16 lanes x 8 swizzled blocks cover all 32 banks 2-way (free).
__global__ __launch_bounds__(256) void sim_kernel(
    const float* __restrict__ P, const float* __restrict__ H,
    const float* __restrict__ Gp, const float* __restrict__ Gh,
    float* __restrict__ Sp, float* __restrict__ Sgp)
{
  const int orig = blockIdx.x;
  const int wg   = (orig & 7) * (1152 / 8) + (orig >> 3);
  const int tile = wg % 9;
  const int g    = wg / 9;            // b*4 + m*2 + ch
  const int ch   = g & 1;
  const int m    = (g >> 1) & 1;
  const int b    = g >> 2;

  const float* X = m ? Gp : P;
  const float* Y = m ? Gh : H;
  float* O = (m ? Sgp : Sp) + (size_t)ch * A1;

  const int ty = tile / 3, tx = tile % 3;
  const int brow = ty * 64, bcol = tx * 64;

  __shared__ unsigned short Ah[64][64], Al[64][64], Bh[64][64], Bl[64][64];

  const int tid  = threadIdx.x;
  const int r    = tid >> 2, q = tid & 3;
  const int lane = tid & 63, wid = tid >> 6;
  const int wm   = wid >> 1, wn = wid & 1;
  const int lr   = lane & 15, kg = lane >> 4;

  f32x4 acc[2][2] = {};

  const float* Xbase = X + (size_t)(b * L + brow + r) * Dk;
  const float* Ybase = Y + (size_t)(b * L + bcol + r) * Dk;
  const int k0beg = ch * 512;

  float4 xv[4], yv[4];

  auto load_regs = [&](int k0){
    #pragma unroll
    for (int j = 0; j < 4; ++j){
      const int c = (q + 4 * j) * 4;
      xv[j] = *reinterpret_cast<const float4*>(Xbase + k0 + c);
      yv[j] = *reinterpret_cast<const float4*>(Ybase + k0 + c);
    }
  };
  auto split_pack = [](const float4& v, uint2& hi, uint2& lo){
    unsigned ux = __float_as_uint(v.x), uy = __float_as_uint(v.y);
    unsigned uz = __float_as_uint(v.z), uw = __float_as_uint(v.w);
    float lx = v.x - __uint_as_float(ux & 0xFFFF0000u);
    float ly = v.y - __uint_as_float(uy & 0xFFFF0000u);
    float lz = v.z - __uint_as_float(uz & 0xFFFF0000u);
    float lw = v.w - __uint_as_float(uw & 0xFFFF0000u);
    hi.x = pack_hi16(ux, uy);
    hi.y = pack_hi16(uz, uw);
    lo.x = pack_hi16(__float_as_uint(lx), __float_as_uint(ly));
    lo.y = pack_hi16(__float_as_uint(lz), __float_as_uint(lw));
  };
  auto convert_store = [&](){
    #pragma unroll
    for (int j = 0; j < 4; ++j){
      const int c  = (q + 4 * j) * 4;                         // short idx
      const int cs = ((((c >> 3) ^ (r & 7)) << 3) | (c & 7)); // swizzled
      uint2 hi, lo;
      split_pack(xv[j], hi, lo);
      *reinterpret_cast<uint2*>(&Ah[r][cs]) = hi;
      *reinterpret_cast<uint2*>(&Al[r][cs]) = lo;
      split_pack(yv[j], hi, lo);
      *reinterpret_cast<uint2*>(&Bh[r][cs]) = hi;
      *reinterpret_cast<uint2*>(&Bl[r][cs]) = lo;
    }
  };

  load_regs(k0beg);
  convert_store();
  __syncthreads();

  const int rowA0 = wm * 32 + lr, rowA1 = rowA0 + 16;
  const int rowB0 = wn * 32 + lr, rowB1 = rowB0 + 16;

  for (int chunk = 0; chunk < 8; ++chunk){
    if (chunk < 7) load_regs(k0beg + (chunk + 1) * 64);   // in flight over MFMA

    #pragma unroll
    for (int kk = 0; kk < 64; kk += 32){
      const int kb = (kk + kg * 8) >> 3;                  // 16B block index
      bf16x8 ah[2], al[2], bh[2], bl[2];
      ah[0] = ldfrag(&Ah[rowA0][(kb ^ (rowA0 & 7)) << 3]);
      ah[1] = ldfrag(&Ah[rowA1][(kb ^ (rowA1 & 7)) << 3]);
      al[0] = ldfrag(&Al[rowA0][(kb ^ (rowA0 & 7)) << 3]);
      al[1] = ldfrag(&Al[rowA1][(kb ^ (rowA1 & 7)) << 3]);
      bh[0] = ldfrag(&Bh[rowB0][(kb ^ (rowB0 & 7)) << 3]);
      bh[1] = ldfrag(&Bh[rowB1][(kb ^ (rowB1 & 7)) << 3]);
      bl[0] = ldfrag(&Bl[rowB0][(kb ^ (rowB0 & 7)) << 3]);
      bl[1] = ldfrag(&Bl[rowB1][(kb ^ (rowB1 & 7)) << 3]);
      #pragma unroll
      for (int tm = 0; tm < 2; ++tm)
        #pragma unroll
        for (int tn = 0; tn < 2; ++tn){
          acc[tm][tn] = __builtin_amdgcn_mfma_f32_16x16x32_bf16(ah[tm], bh[tn], acc[tm][tn], 0, 0, 0);
          acc[tm][tn] = __builtin_amdgcn_mfma_f32_16x16x32_bf16(ah[tm], bl[tn], acc[tm][tn], 0, 0, 0);
          acc[tm][tn] = __builtin_amdgcn_mfma_f32_16x16x32_bf16(al[tm], bh[tn], acc[tm][tn], 0, 0, 0);
        }
    }
    __syncthreads();
    if (chunk < 7){
      convert_store();
      __syncthreads();
    }
  }

  float* Ob = O + (size_t)b * L * L;
  #pragma unroll
  for (int tm = 0; tm < 2; ++tm)
    #pragma unroll
    for (int tn = 0; tn < 2; ++tn){
      const int row0 = brow + wm * 32 + tm * 16 + kg * 4;
      const int col  = bcol + wn * 32 + tn * 16 + lr;
      #pragma unroll
      for (int i = 0; i < 4; ++i)
        Ob[(size_t)(row0 + i) * L + col] = acc[tm][tn][i];
    }
}

// ---- kernel 2: row-wise masked softmax; sums 2 K-partials at load ----------
__global__ __launch_bounds__(256) void row_softmax(
    const float* __restrict__ Sp, const float* __restrict__ Sgp,
    const float* __restrict__ hmask,
    float* __restrict__ o7, float* __restrict__ o9, float* __restrict__ o1,
    ushort_t* __restrict__ w1, ushort_t* __restrict__ w9)
{
  const int b    = blockIdx.y;
  const int p    = blockIdx.x * 4 + (threadIdx.x >> 6);
  const int lane = threadIdx.x & 63;
  const size_t rowoff = ((size_t)b * L + p) * L;
  const float* sr  = Sp  + rowoff;
  const float* sgr = Sgp + rowoff;
  const float* mk  = hmask + (size_t)b * L;

  float m[3], v[3], vg[3];
  #pragma unroll
  for (int j = 0; j < 3; ++j){
    const int h = lane + 64 * j;
    const float mm = mk[h];
    m[j]  = mm;
    v[j]  = (sr [h] + sr [A1 + h]) * mm;
    vg[j] = (sgr[h] + sgr[A1 + h]) * mm;
  }
  float M  = fmaxf(fmaxf(v[0],  v[1]),  v[2]);
  float Mg = fmaxf(fmaxf(vg[0], vg[1]), vg[2]);
  #pragma unroll
  for (int off = 32; off; off >>= 1){
    M  = fmaxf(M,  __shfl_xor(M,  off));
    Mg = fmaxf(Mg, __shfl_xor(Mg, off));
  }
  float e[3], eg[3];
  float Z = 0.f, Zg = 0.f, Ein = 0.f, Eing = 0.f;
  #pragma unroll
  for (int j = 0; j < 3; ++j){
    e[j]  = expf(v[j]  - M);
    eg[j] = expf(vg[j] - Mg);
    Z  += e[j];  Ein  += m[j] * e[j];
    Zg += eg[j]; Eing += m[j] * eg[j];
  }
  #pragma unroll
  for (int off = 32; off; off >>= 1){
    Z    += __shfl_xor(Z,    off);
    Zg   += __shfl_xor(Zg,   off);
    Ein  += __shfl_xor(Ein,  off);
    Eing += __shfl_xor(Eing, off);
  }
  const float inv  = 1.f / (Ein  + 1e-13f * Z);
  const float invg = 1.f / (Eing + 1e-13f * Zg);
  #pragma unroll
  for (int j = 0; j < 3; ++j){
    const int h = lane + 64 * j;
    const float rj  = m[j] * e[j]  * inv;
    const float rgj = m[j] * eg[j] * invg;
    o7[rowoff + h] = rj;
    o9[rowoff + h] = rgj;
    o1[rowoff + h] = rj + rgj;
    if (w1){
      w1[rowoff + h] = f2bf(rj + rgj);
      w9[rowoff + h] = f2bf(rgj);
    }
  }
}

// ---- kernel 3: col-wise masked softmax; sums 2 K-partials at load ----------
__global__ __launch_bounds__(256) void col_softmax(
    const float* __restrict__ Sp, const float* __restrict__ Sgp,
    const float* __restrict__ pmask,
    float* __restrict__ o8, float* __restrict__ o10, float* __restrict__ o2,
    ushort_t* __restrict__ w2, ushort_t* __restrict__ w10)
{
  __shared__ float Ts[192][33], Tg[192][33];
  const int b  = blockIdx.y;
  const int h0 = blockIdx.x * 32;
  const int tid = threadIdx.x;
  const size_t boff = (size_t)b * L * L;

  for (int i = tid; i < 192 * 8; i += 256){
    const int rr = i >> 3, qq = i & 7;
    const size_t base = boff + (size_t)rr * L + h0 + qq * 4;
    float4 a  = *reinterpret_cast<const float4*>(&Sp [base]);
    float4 a2 = *reinterpret_cast<const float4*>(&Sp [A1 + base]);
    float4 g  = *reinterpret_cast<const float4*>(&Sgp[base]);
    float4 g2 = *reinterpret_cast<const float4*>(&Sgp[A1 + base]);
    a.x += a2.x; a.y += a2.y; a.z += a2.z; a.w += a2.w;
    g.x += g2.x; g.y += g2.y; g.z += g2.z; g.w += g2.w;
    Ts[rr][qq*4+0] = a.x; Ts[rr][qq*4+1] = a.y; Ts[rr][qq*4+2] = a.z; Ts[rr][qq*4+3] = a.w;
    Tg[rr][qq*4+0] = g.x; Tg[rr][qq*4+1] = g.y; Tg[rr][qq*4+2] = g.z; Tg[rr][qq*4+3] = g.w;
  }
  __syncthreads();

  const int lane = tid & 63, wid = tid >> 6;
  const float* mk = pmask + (size_t)b * L;
  float m[3];
  #pragma unroll
  for (int j = 0; j < 3; ++j) m[j] = mk[lane + 64 * j];

  for (int c = 0; c < 8; ++c){
    const int hl = wid * 8 + c;
    const int h  = h0 + hl;
    float v[3], vg[3];
    #pragma unroll
    for (int j = 0; j < 3; ++j){
      v[j]  = Ts[lane + 64 * j][hl] * m[j];
      vg[j] = Tg[lane + 64 * j][hl] * m[j];
    }
    float M  = fmaxf(fmaxf(v[0],  v[1]),  v[2]);
    float Mg = fmaxf(fmaxf(vg[0], vg[1]), vg[2]);
    #pragma unroll
    for (int off = 32; off; off >>= 1){
      M  = fmaxf(M,  __shfl_xor(M,  off));
      Mg = fmaxf(Mg, __shfl_xor(Mg, off));
    }
    float e[3], eg[3];
    float Z = 0.f, Zg = 0.f, Ein = 0.f, Eing = 0.f;
    #pragma unroll
    for (int j = 0; j < 3; ++j){
      e[j]  = expf(v[j]  - M);
      eg[j] = expf(vg[j] - Mg);
      Z  += e[j];  Ein  += m[j] * e[j];
      Zg += eg[j]; Eing += m[j] * eg[j];
    }
    #pragma unroll
    for (int off = 32; off; off >>= 1){
      Z    += __shfl_xor(Z,    off);
      Zg   += __shfl_xor(Zg,   off);
      Ein  += __shfl_xor(Ein,  off);
      Eing += __shfl_xor(Eing, off);
    }
    const float inv  = 1.f / (Ein  + 1e-13f * Z);
    const float invg = 1.f / (Eing + 1e-13f * Zg);
    const size_t rowoff = ((size_t)b * L + h) * L;
    #pragma unroll
    for (int j = 0; j < 3; ++j){
      const int pp = lane + 64 * j;
      const float rj  = m[j] * e[j]  * inv;
      const float rgj = m[j] * eg[j] * invg;
      o8 [rowoff + pp] = rj;
      o10[rowoff + pp] = rgj;
      o2 [rowoff + pp] = rj + rgj;
      if (w2){
        w2 [rowoff + pp] = f2bf(rj + rgj);
        w10[rowoff + pp] = f2bf(rgj);
      }
    }
  }
}

// ---- kernel 4: attended = (W @ V) * qmask. Block = 192q x 64d, pipelined. --
// W fragments double-buffered in registers; V staged via reg->LDS split
// (issue loads for ck+1 before MFMA of ck). Vt is [64][64] with the same
// 16B-block XOR swizzle as sim.
__global__ __launch_bounds__(256) void wsum_kernel(
    const float* __restrict__ o1f, const float* __restrict__ o9f,
    const float* __restrict__ o2f, const float* __restrict__ o10f,
    const ushort_t* __restrict__ w1, const ushort_t* __restrict__ w9,
    const ushort_t* __restrict__ w2, const ushort_t* __restrict__ w10,
    const float* __restrict__ Pb, const float* __restrict__ Hb,
    const float* __restrict__ Gp, const float* __restrict__ Gh,
    const float* __restrict__ pmask, const float* __restrict__ hmask,
    float* __restrict__ o3, float* __restrict__ o4,
    float* __restrict__ o5, float* __restrict__ o6)
{
  const int orig = blockIdx.x;
  const int wg   = (orig & 7) * (2048 / 8) + (orig >> 3);
  const int dt   = wg & 15;
  const int gz   = wg >> 4;           // b*4 + z
  const int z    = gz & 3;
  const int b    = gz >> 2;
  const int d0   = dt * 64;

  const float* Wf; const ushort_t* Wh; const float* V; const float* qm; float* O;
  switch (z){
    case 0:  Wf = o1f;  Wh = w1;  V = Hb; qm = pmask; O = o3; break;
    case 1:  Wf = o9f;  Wh = w9;  V = Gh; qm = pmask; O = o4; break;
    case 2:  Wf = o2f;  Wh = w2;  V = Pb; qm = hmask; O = o5; break;
    default: Wf = o10f; Wh = w10; V = Gp; qm = hmask; O = o6; break;
  }

  __shared__ unsigned short Vt[64][64];

  const int tid  = threadIdx.x;
  const int r    = tid >> 2, q = tid & 3;
  const int lane = tid & 63, wv = tid >> 6;
  const int lr   = lane & 15, kg = lane >> 4;

  f32x4 acc[3][4] = {};
  bf16x8 afrA[3][2], afrB[3][2];
  float4 vreg[4];

  auto load_w = [&](int k0, bf16x8 (&afr)[3][2]){
    if (Wh){
      #pragma unroll
      for (int t = 0; t < 3; ++t)
        #pragma unroll
        for (int s = 0; s < 2; ++s){
          const int row = wv * 48 + t * 16 + lr;
          afr[t][s] = *reinterpret_cast<const bf16x8*>(
              Wh + ((size_t)b * L + row) * L + k0 + s * 32 + kg * 8);
        }
    } else {
      #pragma unroll
      for (int t = 0; t < 3; ++t)
        #pragma unroll
        for (int s = 0; s < 2; ++s){
          const int row = wv * 48 + t * 16 + lr;
          const float* wp = Wf + ((size_t)b * L + row) * L + k0 + s * 32 + kg * 8;
          float4 x0 = *reinterpret_cast<const float4*>(wp);
          float4 x1 = *reinterpret_cast<const float4*>(wp + 4);
          bf16x8 vv;
          vv[0] = f2bf(x0.x); vv[1] = f2bf(x0.y); vv[2] = f2bf(x0.z); vv[3] = f2bf(x0.w);
          vv[4] = f2bf(x1.x); vv[5] = f2bf(x1.y); vv[6] = f2bf(x1.z); vv[7] = f2bf(x1.w);
          afr[t][s] = vv;
        }
    }
  };
  auto load_v = [&](int k0){
    #pragma unroll
    for (int j = 0; j < 4; ++j){
      const int dcol = (q + 4 * j) * 4;
      vreg[j] = *reinterpret_cast<const float4*>(
          V + ((size_t)b * L + k0 + r) * Dk + d0 + dcol);
    }
  };
  auto store_v = [&](){
    #pragma unroll
    for (int j = 0; j < 4; ++j){
      const int dcol = (q + 4 * j) * 4;
      unsigned t0 = __float_as_uint(vreg[j].x) >> 16;
      unsigned t1 = __float_as_uint(vreg[j].y) >> 16;
      unsigned t2 = __float_as_uint(vreg[j].z) >> 16;
      unsigned t3 = __float_as_uint(vreg[j].w) >> 16;
      #pragma unroll
      for (int i = 0; i < 4; ++i){
        const int d  = dcol + i;
        const int cs = ((((r >> 3) ^ (d & 7)) << 3) | (r & 7));
        Vt[d][cs] = (ushort_t)(i == 0 ? t0 : i == 1 ? t1 : i == 2 ? t2 : t3);
      }
    }
  };
  auto mfma_step = [&](bf16x8 (&afr)[3][2]){
    #pragma unroll
    for (int s = 0; s < 2; ++s){
      const int kb = (s * 32 + kg * 8) >> 3;
      bf16x8 bfr[4];
      #pragma unroll
      for (int n = 0; n < 4; ++n){
        const int d = n * 16 + lr;
        bfr[n] = ldfrag(&Vt[d][(kb ^ (d & 7)) << 3]);
      }
      #pragma unroll
      for (int t = 0; t < 3; ++t)
        #pragma unroll
        for (int n = 0; n < 4; ++n)
          acc[t][n] = __builtin_amdgcn_mfma_f32_16x16x32_bf16(afr[t][s], bfr[n], acc[t][n], 0, 0, 0);
    }
  };

  // pipelined 3-chunk K loop
  load_w(0, afrA); load_v(0);
  store_v();
  __syncthreads();
  load_w(64, afrB); load_v(64);
  mfma_step(afrA);
  __syncthreads();
  store_v();
  __syncthreads();
  load_w(128, afrA); load_v(128);
  mfma_step(afrB);
  __syncthreads();
  store_v();
  __syncthreads();
  mfma_step(afrA);

  #pragma unroll
  for (int t = 0; t < 3; ++t){
    const int row0 = wv * 48 + t * 16 + kg * 4;
    #pragma unroll
    for (int i = 0; i < 4; ++i){
      const int row  = row0 + i;
      const float mv = qm[(size_t)b * L + row];
      #pragma unroll
      for (int n = 0; n < 4; ++n)
        O[((size_t)b * L + row) * Dk + d0 + n * 16 + lr] = acc[t][n][i] * mv;
    }
  }
}

extern "C" void kernel_launch(void* const* d_in, const int* in_sizes, int n_in,
                              void* d_out, int out_size, void* d_ws, size_t ws_size,
                              hipStream_t stream) {
  const float* P  = (const float*)d_in[0];
  const float* pm = (const float*)d_in[1];
  const float* H  = (const float*)d_in[2];
  const float* hm = (const float*)d_in[3];
  const float* Gp = (const float*)d_in[4];
  const float* Gh = (const float*)d_in[5];
  float* out = (float*)d_out;

  float* o1  = out;
  float* o2  = out + A1;
  float* o3  = out + 2 * A1;
  float* o4  = o3 + C1;
  float* o5  = o3 + 2 * C1;
  float* o6  = o3 + 3 * C1;
  float* o7  = o3 + 4 * C1;
  float* o8  = o7 + A1;
  float* o9  = o7 + 2 * A1;
  float* o10 = o7 + 3 * A1;

  // Split-K partials (2 chunks each): S in o5, Sg in o6 (2*A1 <= C1).
  // Consumed by both softmax kernels; overwritten by wsum afterwards.
  float* Sp  = o5;
  float* Sgp = o6;

  ushort_t* wb = (ws_size >= 4 * A1 * sizeof(ushort_t)) ? (ushort_t*)d_ws : nullptr;
  ushort_t* w1  = wb ? wb + 0 * A1 : nullptr;
  ushort_t* w9  = wb ? wb + 1 * A1 : nullptr;
  ushort_t* w2  = wb ? wb + 2 * A1 : nullptr;
  ushort_t* w10 = wb ? wb + 3 * A1 : nullptr;

  sim_kernel <<<dim3(1152),   256, 0, stream>>>(P, H, Gp, Gh, Sp, Sgp);
  row_softmax<<<dim3(48, 32), 256, 0, stream>>>(Sp, Sgp, hm, o7, o9, o1, w1, w9);
  col_softmax<<<dim3(6, 32),  256, 0, stream>>>(Sp, Sgp, pm, o8, o10, o2, w2, w10);
  wsum_kernel<<<dim3(2048),   256, 0, stream>>>(o1, o9, o2, o10, w1, w9, w2, w10,
                                                P, H, Gp, Gh, pm, hm, o3, o4, o5, o6);
}

// Round 7
// 87.672 us; speedup vs baseline: 1.0871x; 1.0871x over previous
//
#include <hip/hip_runtime.h>

constexpr int Bb = 32;
constexpr int L  = 192;
constexpr int Dk = 1024;
constexpr size_t A1 = (size_t)Bb * L * L;   // elems of one attn matrix
constexpr size_t C1 = (size_t)Bb * L * Dk;  // elems of one attended matrix

typedef short bf16x8 __attribute__((ext_vector_type(8)));
typedef float f32x4  __attribute__((ext_vector_type(4)));
typedef unsigned short ushort_t;

__device__ __forceinline__ unsigned short f2bf(float x){
  unsigned u = __float_as_uint(x);
  u = (u + 0x7FFFu + ((u >> 16) & 1u)) >> 16;
  return (unsigned short)u;
}
__device__ __forceinline__ bf16x8 ldfrag(const unsigned short* p){
  return *reinterpret_cast<const bf16x8*>(p);
}
// pack bf16-truncations of (a,b) into one u32: low16 = hi-bits(a), high16 = hi-bits(b)
__device__ __forceinline__ unsigned pack_hi16(unsigned ua, unsigned ub){
  return __builtin_amdgcn_perm(ua, ub, 0x03020706u);
}

// ---- kernel 1: split-K similarity, reg-prefetch pipeline + XCD swizzle -----
// (identical to the 90.6 us round-5 version)
__global__ __launch_bounds__(256) void sim_kernel(
    const float* __restrict__ P, const float* __restrict__ H,
    const float* __restrict__ Gp, const float* __restrict__ Gh,
    float* __restrict__ Sp, float* __restrict__ Sgp)
{
  const int orig = blockIdx.x;
  const int wg   = (orig & 7) * (1152 / 8) + (orig >> 3);
  const int tile = wg % 9;
  const int g    = wg / 9;            // b*4 + m*2 + ch
  const int ch   = g & 1;
  const int m    = (g >> 1) & 1;
  const int b    = g >> 2;

  const float* X = m ? Gp : P;
  const float* Y = m ? Gh : H;
  float* O = (m ? Sgp : Sp) + (size_t)ch * A1;

  const int ty = tile / 3, tx = tile % 3;
  const int brow = ty * 64, bcol = tx * 64;

  __shared__ unsigned short Ah[64][72], Al[64][72], Bh[64][72], Bl[64][72];

  const int tid  = threadIdx.x;
  const int r    = tid >> 2, q = tid & 3;
  const int lane = tid & 63, wid = tid >> 6;
  const int wm   = wid >> 1, wn = wid & 1;
  const int lr   = lane & 15, kg = lane >> 4;

  f32x4 acc[2][2] = {};

  const float* Xbase = X + (size_t)(b * L + brow + r) * Dk;
  const float* Ybase = Y + (size_t)(b * L + bcol + r) * Dk;
  const int k0beg = ch * 512;

  float4 xv[4], yv[4];

  auto load_regs = [&](int k0){
    #pragma unroll
    for (int j = 0; j < 4; ++j){
      const int c = (q + 4 * j) * 4;
      xv[j] = *reinterpret_cast<const float4*>(Xbase + k0 + c);
      yv[j] = *reinterpret_cast<const float4*>(Ybase + k0 + c);
    }
  };
  auto split_pack = [](const float4& v, uint2& hi, uint2& lo){
    unsigned ux = __float_as_uint(v.x), uy = __float_as_uint(v.y);
    unsigned uz = __float_as_uint(v.z), uw = __float_as_uint(v.w);
    float lx = v.x - __uint_as_float(ux & 0xFFFF0000u);
    float ly = v.y - __uint_as_float(uy & 0xFFFF0000u);
    float lz = v.z - __uint_as_float(uz & 0xFFFF0000u);
    float lw = v.w - __uint_as_float(uw & 0xFFFF0000u);
    hi.x = pack_hi16(ux, uy);
    hi.y = pack_hi16(uz, uw);
    lo.x = pack_hi16(__float_as_uint(lx), __float_as_uint(ly));
    lo.y = pack_hi16(__float_as_uint(lz), __float_as_uint(lw));
  };
  auto convert_store = [&](){
    #pragma unroll
    for (int j = 0; j < 4; ++j){
      const int c = (q + 4 * j) * 4;
      uint2 hi, lo;
      split_pack(xv[j], hi, lo);
      *reinterpret_cast<uint2*>(&Ah[r][c]) = hi;
      *reinterpret_cast<uint2*>(&Al[r][c]) = lo;
      split_pack(yv[j], hi, lo);
      *reinterpret_cast<uint2*>(&Bh[r][c]) = hi;
      *reinterpret_cast<uint2*>(&Bl[r][c]) = lo;
    }
  };

  load_regs(k0beg);
  convert_store();
  __syncthreads();

  for (int chunk = 0; chunk < 8; ++chunk){
    if (chunk < 7) load_regs(k0beg + (chunk + 1) * 64);   // in flight over MFMA

    #pragma unroll
    for (int kk = 0; kk < 64; kk += 32){
      const int ki = kk + kg * 8;
      bf16x8 ah[2], al[2], bh[2], bl[2];
      ah[0] = ldfrag(&Ah[wm * 32 +      lr][ki]);
      ah[1] = ldfrag(&Ah[wm * 32 + 16 + lr][ki]);
      al[0] = ldfrag(&Al[wm * 32 +      lr][ki]);
      al[1] = ldfrag(&Al[wm * 32 + 16 + lr][ki]);
      bh[0] = ldfrag(&Bh[wn * 32 +      lr][ki]);
      bh[1] = ldfrag(&Bh[wn * 32 + 16 + lr][ki]);
      bl[0] = ldfrag(&Bl[wn * 32 +      lr][ki]);
      bl[1] = ldfrag(&Bl[wn * 32 + 16 + lr][ki]);
      #pragma unroll
      for (int tm = 0; tm < 2; ++tm)
        #pragma unroll
        for (int tn = 0; tn < 2; ++tn){
          acc[tm][tn] = __builtin_amdgcn_mfma_f32_16x16x32_bf16(ah[tm], bh[tn], acc[tm][tn], 0, 0, 0);
          acc[tm][tn] = __builtin_amdgcn_mfma_f32_16x16x32_bf16(ah[tm], bl[tn], acc[tm][tn], 0, 0, 0);
          acc[tm][tn] = __builtin_amdgcn_mfma_f32_16x16x32_bf16(al[tm], bh[tn], acc[tm][tn], 0, 0, 0);
        }
    }
    __syncthreads();
    if (chunk < 7){
      convert_store();
      __syncthreads();
    }
  }

  float* Ob = O + (size_t)b * L * L;
  #pragma unroll
  for (int tm = 0; tm < 2; ++tm)
    #pragma unroll
    for (int tn = 0; tn < 2; ++tn){
      const int row0 = brow + wm * 32 + tm * 16 + kg * 4;
      const int col  = bcol + wn * 32 + tn * 16 + lr;
      #pragma unroll
      for (int i = 0; i < 4; ++i)
        Ob[(size_t)(row0 + i) * L + col] = acc[tm][tn][i];
    }
}

// ---- kernel 2: fused masked softmax (row + col parts in one launch) --------
// blockIdx.x < 48  -> row-softmax block (4 rows p, hyp mask)
// blockIdx.x >= 48 -> col-softmax block (16 cols h via LDS transpose, prem mask)
// Parts are fully independent (disjoint outputs); branch is block-uniform.
__global__ __launch_bounds__(256) void softmax_kernel(
    const float* __restrict__ Sp, const float* __restrict__ Sgp,
    const float* __restrict__ pmask, const float* __restrict__ hmask,
    float* __restrict__ o7, float* __restrict__ o9, float* __restrict__ o1,
    ushort_t* __restrict__ w1, ushort_t* __restrict__ w9,
    float* __restrict__ o8, float* __restrict__ o10, float* __restrict__ o2,
    ushort_t* __restrict__ w2, ushort_t* __restrict__ w10)
{
  const int b   = blockIdx.y;
  const int tid = threadIdx.x;

  if (blockIdx.x < 48){
    // ---------------- row part ----------------
    const int p    = blockIdx.x * 4 + (tid >> 6);
    const int lane = tid & 63;
    const size_t rowoff = ((size_t)b * L + p) * L;
    const float* sr  = Sp  + rowoff;
    const float* sgr = Sgp + rowoff;
    const float* mk  = hmask + (size_t)b * L;

    float m[3], v[3], vg[3];
    #pragma unroll
    for (int j = 0; j < 3; ++j){
      const int h = lane + 64 * j;
      const float mm = mk[h];
      m[j]  = mm;
      v[j]  = (sr [h] + sr [A1 + h]) * mm;
      vg[j] = (sgr[h] + sgr[A1 + h]) * mm;
    }
    float M  = fmaxf(fmaxf(v[0],  v[1]),  v[2]);
    float Mg = fmaxf(fmaxf(vg[0], vg[1]), vg[2]);
    #pragma unroll
    for (int off = 32; off; off >>= 1){
      M  = fmaxf(M,  __shfl_xor(M,  off));
      Mg = fmaxf(Mg, __shfl_xor(Mg, off));
    }
    float e[3], eg[3];
    float Z = 0.f, Zg = 0.f, Ein = 0.f, Eing = 0.f;
    #pragma unroll
    for (int j = 0; j < 3; ++j){
      e[j]  = expf(v[j]  - M);
      eg[j] = expf(vg[j] - Mg);
      Z  += e[j];  Ein  += m[j] * e[j];
      Zg += eg[j]; Eing += m[j] * eg[j];
    }
    #pragma unroll
    for (int off = 32; off; off >>= 1){
      Z    += __shfl_xor(Z,    off);
      Zg   += __shfl_xor(Zg,   off);
      Ein  += __shfl_xor(Ein,  off);
      Eing += __shfl_xor(Eing, off);
    }
    const float inv  = 1.f / (Ein  + 1e-13f * Z);
    const float invg = 1.f / (Eing + 1e-13f * Zg);
    #pragma unroll
    for (int j = 0; j < 3; ++j){
      const int h = lane + 64 * j;
      const float rj  = m[j] * e[j]  * inv;
      const float rgj = m[j] * eg[j] * invg;
      o7[rowoff + h] = rj;
      o9[rowoff + h] = rgj;
      o1[rowoff + h] = rj + rgj;
      if (w1){
        w1[rowoff + h] = f2bf(rj + rgj);
        w9[rowoff + h] = f2bf(rgj);
      }
    }
  } else {
    // ---------------- col part ----------------
    __shared__ float Ts[192][17], Tg[192][17];
    const int h0 = (blockIdx.x - 48) * 16;
    const size_t boff = (size_t)b * L * L;

    for (int i = tid; i < 192 * 4; i += 256){
      const int rr = i >> 2, qq = i & 3;
      const size_t base = boff + (size_t)rr * L + h0 + qq * 4;
      float4 a  = *reinterpret_cast<const float4*>(&Sp [base]);
      float4 a2 = *reinterpret_cast<const float4*>(&Sp [A1 + base]);
      float4 g  = *reinterpret_cast<const float4*>(&Sgp[base]);
      float4 g2 = *reinterpret_cast<const float4*>(&Sgp[A1 + base]);
      a.x += a2.x; a.y += a2.y; a.z += a2.z; a.w += a2.w;
      g.x += g2.x; g.y += g2.y; g.z += g2.z; g.w += g2.w;
      Ts[rr][qq*4+0] = a.x; Ts[rr][qq*4+1] = a.y; Ts[rr][qq*4+2] = a.z; Ts[rr][qq*4+3] = a.w;
      Tg[rr][qq*4+0] = g.x; Tg[rr][qq*4+1] = g.y; Tg[rr][qq*4+2] = g.z; Tg[rr][qq*4+3] = g.w;
    }
    __syncthreads();

    const int lane = tid & 63, wid = tid >> 6;
    const float* mk = pmask + (size_t)b * L;
    float m[3];
    #pragma unroll
    for (int j = 0; j < 3; ++j) m[j] = mk[lane + 64 * j];

    for (int c = 0; c < 4; ++c){
      const int hl = wid * 4 + c;
      const int h  = h0 + hl;
      float v[3], vg[3];
      #pragma unroll
      for (int j = 0; j < 3; ++j){
        v[j]  = Ts[lane + 64 * j][hl] * m[j];
        vg[j] = Tg[lane + 64 * j][hl] * m[j];
      }
      float M  = fmaxf(fmaxf(v[0],  v[1]),  v[2]);
      float Mg = fmaxf(fmaxf(vg[0], vg[1]), vg[2]);
      #pragma unroll
      for (int off = 32; off; off >>= 1){
        M  = fmaxf(M,  __shfl_xor(M,  off));
        Mg = fmaxf(Mg, __shfl_xor(Mg, off));
      }
      float e[3], eg[3];
      float Z = 0.f, Zg = 0.f, Ein = 0.f, Eing = 0.f;
      #pragma unroll
      for (int j = 0; j < 3; ++j){
        e[j]  = expf(v[j]  - M);
        eg[j] = expf(vg[j] - Mg);
        Z  += e[j];  Ein  += m[j] * e[j];
        Zg += eg[j]; Eing += m[j] * eg[j];
      }
      #pragma unroll
      for (int off = 32; off; off >>= 1){
        Z    += __shfl_xor(Z,    off);
        Zg   += __shfl_xor(Zg,   off);
        Ein  += __shfl_xor(Ein,  off);
        Eing += __shfl_xor(Eing, off);
      }
      const float inv  = 1.f / (Ein  + 1e-13f * Z);
      const float invg = 1.f / (Eing + 1e-13f * Zg);
      const size_t rowoff = ((size_t)b * L + h) * L;
      #pragma unroll
      for (int j = 0; j < 3; ++j){
        const int pp = lane + 64 * j;
        const float rj  = m[j] * e[j]  * inv;
        const float rgj = m[j] * eg[j] * invg;
        o8 [rowoff + pp] = rj;
        o10[rowoff + pp] = rgj;
        o2 [rowoff + pp] = rj + rgj;
        if (w2){
          w2 [rowoff + pp] = f2bf(rj + rgj);
          w10[rowoff + pp] = f2bf(rgj);
        }
      }
    }
  }
}

// ---- kernel 4: attended = (W @ V) * qmask. Block = 192q x 64d. -------------
// (identical to the 90.6 us round-5 version)
__global__ __launch_bounds__(256) void wsum_kernel(
    const float* __restrict__ o1f, const float* __restrict__ o9f,
    const float* __restrict__ o2f, const float* __restrict__ o10f,
    const ushort_t* __restrict__ w1, const ushort_t* __restrict__ w9,
    const ushort_t* __restrict__ w2, const ushort_t* __restrict__ w10,
    const float* __restrict__ Pb, const float* __restrict__ Hb,
    const float* __restrict__ Gp, const float* __restrict__ Gh,
    const float* __restrict__ pmask, const float* __restrict__ hmask,
    float* __restrict__ o3, float* __restrict__ o4,
    float* __restrict__ o5, float* __restrict__ o6)
{
  const int orig = blockIdx.x;
  const int wg   = (orig & 7) * (2048 / 8) + (orig >> 3);
  const int dt   = wg & 15;
  const int gz   = wg >> 4;           // b*4 + z
  const int z    = gz & 3;
  const int b    = gz >> 2;
  const int d0   = dt * 64;

  const float* Wf; const ushort_t* Wh; const float* V; const float* qm; float* O;
  switch (z){
    case 0:  Wf = o1f;  Wh = w1;  V = Hb; qm = pmask; O = o3; break;
    case 1:  Wf = o9f;  Wh = w9;  V = Gh; qm = pmask; O = o4; break;
    case 2:  Wf = o2f;  Wh = w2;  V = Pb; qm = hmask; O = o5; break;
    default: Wf = o10f; Wh = w10; V = Gp; qm = hmask; O = o6; break;
  }

  __shared__ unsigned short Vt[64][68];

  const int tid  = threadIdx.x;
  const int r    = tid >> 2, q = tid & 3;
  const int lane = tid & 63, wv = tid >> 6;
  const int lr   = lane & 15, kg = lane >> 4;

  f32x4 acc[3][4] = {};

  for (int ck = 0; ck < 3; ++ck){
    const int k0 = ck * 64;

    bf16x8 afr[3][2];
    if (Wh){
      #pragma unroll
      for (int t = 0; t < 3; ++t)
        #pragma unroll
        for (int s = 0; s < 2; ++s){
          const int row = wv * 48 + t * 16 + lr;
          afr[t][s] = *reinterpret_cast<const bf16x8*>(
              Wh + ((size_t)b * L + row) * L + k0 + s * 32 + kg * 8);
        }
    } else {
      #pragma unroll
      for (int t = 0; t < 3; ++t)
        #pragma unroll
        for (int s = 0; s < 2; ++s){
          const int row = wv * 48 + t * 16 + lr;
          const float* wp = Wf + ((size_t)b * L + row) * L + k0 + s * 32 + kg * 8;
          float4 x0 = *reinterpret_cast<const float4*>(wp);
          float4 x1 = *reinterpret_cast<const float4*>(wp + 4);
          bf16x8 vv;
          vv[0] = f2bf(x0.x); vv[1] = f2bf(x0.y); vv[2] = f2bf(x0.z); vv[3] = f2bf(x0.w);
          vv[4] = f2bf(x1.x); vv[5] = f2bf(x1.y); vv[6] = f2bf(x1.z); vv[7] = f2bf(x1.w);
          afr[t][s] = vv;
        }
    }

    #pragma unroll
    for (int j = 0; j < 4; ++j){
      const int dcol = (q + 4 * j) * 4;
      float4 vvv = *reinterpret_cast<const float4*>(
          V + ((size_t)b * L + k0 + r) * Dk + d0 + dcol);
      Vt[dcol + 0][r] = (ushort_t)(__float_as_uint(vvv.x) >> 16);
      Vt[dcol + 1][r] = (ushort_t)(__float_as_uint(vvv.y) >> 16);
      Vt[dcol + 2][r] = (ushort_t)(__float_as_uint(vvv.z) >> 16);
      Vt[dcol + 3][r] = (ushort_t)(__float_as_uint(vvv.w) >> 16);
    }
    __syncthreads();

    #pragma unroll
    for (int s = 0; s < 2; ++s){
      const int ki = s * 32 + kg * 8;
      bf16x8 bfr[4];
      #pragma unroll
      for (int n = 0; n < 4; ++n)
        bfr[n] = ldfrag(&Vt[n * 16 + lr][ki]);
      #pragma unroll
      for (int t = 0; t < 3; ++t)
        #pragma unroll
        for (int n = 0; n < 4; ++n)
          acc[t][n] = __builtin_amdgcn_mfma_f32_16x16x32_bf16(afr[t][s], bfr[n], acc[t][n], 0, 0, 0);
    }
    __syncthreads();
  }

  #pragma unroll
  for (int t = 0; t < 3; ++t){
    const int row0 = wv * 48 + t * 16 + kg * 4;
    #pragma unroll
    for (int i = 0; i < 4; ++i){
      const int row  = row0 + i;
      const float mv = qm[(size_t)b * L + row];
      #pragma unroll
      for (int n = 0; n < 4; ++n)
        O[((size_t)b * L + row) * Dk + d0 + n * 16 + lr] = acc[t][n][i] * mv;
    }
  }
}

extern "C" void kernel_launch(void* const* d_in, const int* in_sizes, int n_in,
                              void* d_out, int out_size, void* d_ws, size_t ws_size,
                              hipStream_t stream) {
  const float* P  = (const float*)d_in[0];
  const float* pm = (const float*)d_in[1];
  const float* H  = (const float*)d_in[2];
  const float* hm = (const float*)d_in[3];
  const float* Gp = (const float*)d_in[4];
  const float* Gh = (const float*)d_in[5];
  float* out = (float*)d_out;

  float* o1  = out;
  float* o2  = out + A1;
  float* o3  = out + 2 * A1;
  float* o4  = o3 + C1;
  float* o5  = o3 + 2 * C1;
  float* o6  = o3 + 3 * C1;
  float* o7  = o3 + 4 * C1;
  float* o8  = o7 + A1;
  float* o9  = o7 + 2 * A1;
  float* o10 = o7 + 3 * A1;

  // Split-K partials (2 chunks each): S in o5, Sg in o6 (2*A1 <= C1).
  // Consumed by the fused softmax kernel; overwritten by wsum afterwards.
  float* Sp  = o5;
  float* Sgp = o6;

  ushort_t* wb = (ws_size >= 4 * A1 * sizeof(ushort_t)) ? (ushort_t*)d_ws : nullptr;
  ushort_t* w1  = wb ? wb + 0 * A1 : nullptr;
  ushort_t* w9  = wb ? wb + 1 * A1 : nullptr;
  ushort_t* w2  = wb ? wb + 2 * A1 : nullptr;
  ushort_t* w10 = wb ? wb + 3 * A1 : nullptr;

  sim_kernel    <<<dim3(1152),   256, 0, stream>>>(P, H, Gp, Gh, Sp, Sgp);
  softmax_kernel<<<dim3(60, 32), 256, 0, stream>>>(Sp, Sgp, pm, hm,
                                                   o7, o9, o1, w1, w9,
                                                   o8, o10, o2, w2, w10);
  wsum_kernel   <<<dim3(2048),   256, 0, stream>>>(o1, o9, o2, o10, w1, w9, w2, w10,
                                                   P, H, Gp, Gh, pm, hm, o3, o4, o5, o6);
}